// Round 1
// 52803.894 us; speedup vs baseline: 1.0845x; 1.0845x over previous
//
#include <hip/hip_runtime.h>

// Problem constants
#define HH 512
#define BB 128
#define TT 512
#define LL 4
#define JJ 2
#define NBLK 128   // persistent grid size (must match launch)

typedef _Float16 f16;
typedef __attribute__((ext_vector_type(8))) _Float16 f16x8;
typedef __attribute__((ext_vector_type(4))) float f32x4;

// ---------------------------------------------------------------------------
// Weight convert + transpose: src fp32 [mat][K][N] -> dst fp16 [mat][N][K]
// ---------------------------------------------------------------------------
__global__ __launch_bounds__(256) void wt_transpose_cvt(
    const float* __restrict__ src, f16* __restrict__ dst, int K, int N)
{
    __shared__ f16 tile[32][33];
    const size_t mat = blockIdx.z;
    const float* s = src + mat * (size_t)K * N;
    f16* d = dst + mat * (size_t)K * N;
    const int k0 = blockIdx.x * 32, n0 = blockIdx.y * 32;
    const int tx = threadIdx.x & 31, ty = threadIdx.x >> 5; // 32 x 8
#pragma unroll
    for (int i = 0; i < 4; i++) {
        int k = k0 + ty + 8 * i;
        tile[ty + 8 * i][tx] = (f16)s[(size_t)k * N + n0 + tx];
    }
    __syncthreads();
#pragma unroll
    for (int i = 0; i < 4; i++) {
        int n = n0 + ty + 8 * i;
        d[(size_t)n * K + k0 + tx] = tile[tx][ty + 8 * i];
    }
}

// ---------------------------------------------------------------------------
// Persistent-kernel parameter block
// ---------------------------------------------------------------------------
struct PK {
    const float* H0in;
    const float* lin_b;
    const float* g0_b;
    const float* g1_b;
    const f16* linT;   // [L][J][2048][1024]
    const f16* g0T;    // [L][J][512][1024]
    const f16* g1T;
    float* H0out;      // (B,T,H)
    float* H1st;       // (B,L,H) f32 state, lives in d_out
    f16*   h1f16;      // [L][B][H] fp16 mirror of H1st
    float* pipe32;     // [2][L][B][H] h0 between layers (parity d&1)
    f16*   pipe16;
    float* h0m32; f16* h0m16;   // [L][B][H] j-intermediate h0
    float* h1m32; f16* h1m16;   // [L][B][H] j-intermediate h1
    f16* a0hi; f16* a1hi;       // [L][B][H] gated halves h1*r, h0*q
    float* z0; float* z1;       // [L][B][H] gates
    f16* h0c;                   // [2][B][H] fp16 of H0in[:,t,:] (parity t&1)
    unsigned* barc;             // barrier count
    unsigned* barg;             // barrier generation (separate cacheline)
};

// Device-scope grid barrier (all NBLK blocks co-resident: 128 blocks on 256 CUs).
__device__ inline void gsync(unsigned* cnt, unsigned* gen)
{
    __syncthreads();
    if (threadIdx.x == 0) {
        __threadfence();  // release: make this block's writes visible device-wide
        unsigned g = __hip_atomic_load(gen, __ATOMIC_RELAXED, __HIP_MEMORY_SCOPE_AGENT);
        unsigned prev = __hip_atomic_fetch_add(cnt, 1u, __ATOMIC_RELAXED, __HIP_MEMORY_SCOPE_AGENT);
        if (prev == NBLK - 1) {
            __hip_atomic_store(cnt, 0u, __ATOMIC_RELAXED, __HIP_MEMORY_SCOPE_AGENT);
            __threadfence();
            __hip_atomic_store(gen, g + 1u, __ATOMIC_RELAXED, __HIP_MEMORY_SCOPE_AGENT);
        } else {
            while (__hip_atomic_load(gen, __ATOMIC_RELAXED, __HIP_MEMORY_SCOPE_AGENT) == g)
                __builtin_amdgcn_s_sleep(2);
        }
        __threadfence();  // acquire: invalidate caches before reading others' data
    }
    __syncthreads();
}

// ---------------------------------------------------------------------------
// Stage 1 tile: g = sigmoid([h0|h1] @ lin_w + b). M=128, K=1024, BN=64.
// A operand read as fp16 mirrors (alo = k<512 source, ahi = k>=512 source).
// Epilogue by column class: 0 -> z0, 1 -> z1, 2 -> a0hi = h1*r, 3 -> a1hi = h0*q
// ---------------------------------------------------------------------------
__device__ __forceinline__ void s1_tile(
    const f16* __restrict__ alo, const f16* __restrict__ ahi,
    const f16* __restrict__ wT, const float* __restrict__ bias,
    float* __restrict__ z0, float* __restrict__ z1,
    f16* __restrict__ a0hi, f16* __restrict__ a1hi,
    int n0, int tid, int lane, int wid,
    f16 (*Al)[72], f16 (*Bl)[72])
{
    const int wm = wid & 1;
    const int wn = wid >> 1;
    f32x4 acc[4][2] = {};
    const int kc = tid & 7;   // 8 k-groups of 8 halves = 64 k
    const int rb = tid >> 3;  // 32 row base

    for (int k0 = 0; k0 < 1024; k0 += 64) {
        const f16* ab = (k0 < 512 ? alo : ahi) + (k0 & 511) + kc * 8;
#pragma unroll
        for (int i = 0; i < 4; i++) {
            int rr = rb + 32 * i;
            *(f16x8*)(&Al[rr][kc * 8]) = *(const f16x8*)(ab + (size_t)rr * HH);
        }
#pragma unroll
        for (int i = 0; i < 2; i++) {
            int nn = rb + 32 * i;
            *(f16x8*)(&Bl[nn][kc * 8]) = *(const f16x8*)(wT + (size_t)(n0 + nn) * 1024 + k0 + kc * 8);
        }
        __syncthreads();
#pragma unroll
        for (int ks = 0; ks < 64; ks += 32) {
            const int kl = ks + (lane >> 4) * 8;
            f16x8 af[4], bf[2];
#pragma unroll
            for (int fm = 0; fm < 4; fm++)
                af[fm] = *(const f16x8*)(&Al[wm * 64 + fm * 16 + (lane & 15)][kl]);
#pragma unroll
            for (int fn = 0; fn < 2; fn++)
                bf[fn] = *(const f16x8*)(&Bl[wn * 32 + fn * 16 + (lane & 15)][kl]);
#pragma unroll
            for (int fm = 0; fm < 4; fm++)
#pragma unroll
                for (int fn = 0; fn < 2; fn++)
                    acc[fm][fn] = __builtin_amdgcn_mfma_f32_16x16x32_f16(
                        af[fm], bf[fn], acc[fm][fn], 0, 0, 0);
        }
        __syncthreads();
    }

    const int cls = n0 >> 9;
#pragma unroll
    for (int fm = 0; fm < 4; fm++) {
#pragma unroll
        for (int fn = 0; fn < 2; fn++) {
#pragma unroll
            for (int r = 0; r < 4; r++) {
                int m = wm * 64 + fm * 16 + (lane >> 4) * 4 + r;
                int n = n0 + wn * 32 + fn * 16 + (lane & 15);
                float x = acc[fm][fn][r] + bias[n];
                float s = 1.0f / (1.0f + __expf(-x));
                int nn = n & 511;
                if (cls == 0)      z0[m * 512 + nn] = s;
                else if (cls == 1) z1[m * 512 + nn] = s;
                else if (cls == 2) a0hi[m * 512 + nn] = (f16)((float)ahi[m * 512 + nn] * s);
                else               a1hi[m * 512 + nn] = (f16)((float)alo[m * 512 + nn] * s);
            }
        }
    }
}

// ---------------------------------------------------------------------------
// Stage 2 tile: hc = tanh(A @ gw + gb); dst = z*hc + (1-z)*old.
// A = [alo | ahi] fp16 mirrors. Writes fp32 master + optional fp16 mirror.
// M=128, K=1024, BN=32.
// ---------------------------------------------------------------------------
__device__ __forceinline__ void s2_tile(
    const f16* __restrict__ alo, const f16* __restrict__ ahi,
    const f16* __restrict__ wT, const float* __restrict__ bias,
    const float* __restrict__ zg, const float* __restrict__ oldp, int olds,
    float* __restrict__ dst32, int dsts, f16* __restrict__ dst16,
    int n0, int tid, int lane, int wid,
    f16 (*Al)[72], f16 (*Bl)[72])
{
    const int wm = wid & 1;
    const int wn = wid >> 1;
    f32x4 acc[4] = {};
    const int kc = tid & 7;
    const int rb = tid >> 3;

    for (int k0 = 0; k0 < 1024; k0 += 64) {
        const f16* ab = (k0 < 512 ? alo : ahi) + (k0 & 511) + kc * 8;
#pragma unroll
        for (int i = 0; i < 4; i++) {
            int rr = rb + 32 * i;
            *(f16x8*)(&Al[rr][kc * 8]) = *(const f16x8*)(ab + (size_t)rr * HH);
        }
        *(f16x8*)(&Bl[rb][kc * 8]) = *(const f16x8*)(wT + (size_t)(n0 + rb) * 1024 + k0 + kc * 8);
        __syncthreads();
#pragma unroll
        for (int ks = 0; ks < 64; ks += 32) {
            const int kl = ks + (lane >> 4) * 8;
            f16x8 bf = *(const f16x8*)(&Bl[wn * 16 + (lane & 15)][kl]);
#pragma unroll
            for (int fm = 0; fm < 4; fm++) {
                f16x8 af = *(const f16x8*)(&Al[wm * 64 + fm * 16 + (lane & 15)][kl]);
                acc[fm] = __builtin_amdgcn_mfma_f32_16x16x32_f16(af, bf, acc[fm], 0, 0, 0);
            }
        }
        __syncthreads();
    }

#pragma unroll
    for (int fm = 0; fm < 4; fm++) {
#pragma unroll
        for (int r = 0; r < 4; r++) {
            int m = wm * 64 + fm * 16 + (lane >> 4) * 4 + r;
            int n = n0 + wn * 16 + (lane & 15);
            float hc  = tanhf(acc[fm][r] + bias[n]);
            float zv  = zg[m * 512 + n];
            float old = oldp[(size_t)m * olds + n];
            float v = zv * hc + (1.0f - zv) * old;
            dst32[(size_t)m * dsts + n] = v;
            if (dst16) dst16[m * 512 + n] = (f16)v;
        }
    }
}

// ---------------------------------------------------------------------------
// Persistent kernel: whole wavefront (515 diagonals x J x {S1,S2}) in one
// launch; phases separated by device-scope grid barriers. Eliminates ~2060
// kernel-launch boundaries (~25 us each -> ~2-3 us barriers).
// ---------------------------------------------------------------------------
__global__ __launch_bounds__(256, 1) void lattice_persistent(PK P)
{
    __shared__ __attribute__((aligned(16))) f16 Al[128][72];
    __shared__ __attribute__((aligned(16))) f16 Bl[64][72];

    const int tid  = threadIdx.x;
    const int lane = tid & 63;
    const int wid  = tid >> 6;
    const int bid  = blockIdx.x;

    // ---- prologue: zero h1 fp16 mirror; convert H0in[:,0,:] -> h0c[0]
    {
        int g = bid * 256 + tid;                 // 0..32767
        f16x8 zz = {};
        ((f16x8*)P.h1f16)[g] = zz;               // 32768 vectors exactly
        int idx = g * 2;                         // 65536 floats, 2 per thread
        int m = idx >> 9;
        int k = idx & 511;
        const float* s = P.H0in + (size_t)m * (TT * HH) + k;  // t = 0
        f16* dd = P.h0c + (size_t)m * HH + k;                 // parity 0
        dd[0] = (f16)s[0];
        dd[1] = (f16)s[1];
    }
    gsync(P.barc, P.barg);

    for (int d = 0; d < TT + LL - 1; ++d) {
        int lmin = d - (TT - 1); if (lmin < 0) lmin = 0;
        int lmax = d < LL - 1 ? d : LL - 1;
        int nc = lmax - lmin + 1;
        for (int j = 0; j < JJ; ++j) {
            // ================= stage 1 phase: nc*32 tiles =================
            int nt1 = nc * 32;
            for (int tile = bid; tile < nt1; tile += NBLK) {
                int l = lmin + (tile >> 5);
                int n0 = (tile & 31) * 64;
                int w = l * JJ + j;
                const f16 *alo, *ahi;
                if (j == 0) {
                    alo = (l == 0) ? P.h0c + (size_t)(d & 1) * (BB * HH)
                                   : P.pipe16 + (size_t)((d & 1) * LL + l) * (BB * HH);
                    ahi = P.h1f16 + (size_t)l * (BB * HH);
                } else {
                    alo = P.h0m16 + (size_t)l * (BB * HH);
                    ahi = P.h1m16 + (size_t)l * (BB * HH);
                }
                s1_tile(alo, ahi,
                        P.linT + (size_t)w * (2048 * 1024),
                        P.lin_b + (size_t)w * 2048,
                        P.z0 + (size_t)l * (BB * HH), P.z1 + (size_t)l * (BB * HH),
                        P.a0hi + (size_t)l * (BB * HH), P.a1hi + (size_t)l * (BB * HH),
                        n0, tid, lane, wid, Al, Bl);
            }
            gsync(P.barc, P.barg);

            // ============ stage 2 phase: nc*32 tiles (+16 conv) ============
            int nt2 = nc * 32;
            bool cv = (j == 1) && (d + 1 < TT);
            int ntt = nt2 + (cv ? 16 : 0);
            for (int tile = bid; tile < ntt; tile += NBLK) {
                if (tile < nt2) {
                    int ci = tile >> 5;
                    int rem = tile & 31;
                    int gi = rem >> 4;          // 0: g0 (-> new h1), 1: g1 (-> new h0)
                    int n0 = (rem & 15) * 32;
                    int l = lmin + ci, t = d - l;
                    int w = l * JJ + j;
                    const f16 *alo, *ahi, *wTp;
                    const float *bp, *zp, *op;
                    int os, ds;
                    float* d32; f16* d16;
                    if (gi == 0) {
                        // g0: A=[h0 | h1*r] -> h0_cap; new h1 = z1*hc + (1-z1)*h1
                        if (j == 0) {
                            alo = (l == 0) ? P.h0c + (size_t)(d & 1) * (BB * HH)
                                           : P.pipe16 + (size_t)((d & 1) * LL + l) * (BB * HH);
                            op = P.H1st + (size_t)l * HH; os = LL * HH;
                            d32 = P.h1m32 + (size_t)l * (BB * HH); ds = HH;
                            d16 = P.h1m16 + (size_t)l * (BB * HH);
                        } else {
                            alo = P.h0m16 + (size_t)l * (BB * HH);
                            op = P.h1m32 + (size_t)l * (BB * HH); os = HH;
                            d32 = P.H1st + (size_t)l * HH; ds = LL * HH;
                            d16 = P.h1f16 + (size_t)l * (BB * HH);
                        }
                        ahi = P.a0hi + (size_t)l * (BB * HH);
                        wTp = P.g0T + (size_t)w * (512 * 1024);
                        bp  = P.g0_b + (size_t)w * 512;
                        zp  = P.z1 + (size_t)l * (BB * HH);
                    } else {
                        // g1: A=[h1 | h0*q] -> h1_cap; new h0 = z0*hc + (1-z0)*h0
                        if (j == 0) {
                            alo = P.h1f16 + (size_t)l * (BB * HH);
                            op = (l == 0) ? P.H0in + (size_t)t * HH
                                          : P.pipe32 + (size_t)((d & 1) * LL + l) * (BB * HH);
                            os = (l == 0) ? (TT * HH) : HH;
                            d32 = P.h0m32 + (size_t)l * (BB * HH); ds = HH;
                            d16 = P.h0m16 + (size_t)l * (BB * HH);
                        } else {
                            alo = P.h1m16 + (size_t)l * (BB * HH);
                            op = P.h0m32 + (size_t)l * (BB * HH); os = HH;
                            if (l == LL - 1) {
                                d32 = P.H0out + (size_t)t * HH; ds = TT * HH; d16 = nullptr;
                            } else {
                                d32 = P.pipe32 + (size_t)(((d + 1) & 1) * LL + (l + 1)) * (BB * HH); ds = HH;
                                d16 = P.pipe16 + (size_t)(((d + 1) & 1) * LL + (l + 1)) * (BB * HH);
                            }
                        }
                        ahi = P.a1hi + (size_t)l * (BB * HH);
                        wTp = P.g1T + (size_t)w * (512 * 1024);
                        bp  = P.g1_b + (size_t)w * 512;
                        zp  = P.z0 + (size_t)l * (BB * HH);
                    }
                    s2_tile(alo, ahi, wTp, bp, zp, op, os, d32, ds, d16,
                            n0, tid, lane, wid, Al, Bl);
                } else {
                    // convert H0in[:, d+1, :] -> h0c[(d+1)&1] for next diagonal
                    int ct = tile - nt2;            // 0..15
                    int tn = d + 1;
                    int m = ct * 8 + (tid >> 5);
                    int k = (tid & 31) * 16;
                    const float* s = P.H0in + (size_t)m * (TT * HH) + (size_t)tn * HH + k;
                    f16* dd = P.h0c + (size_t)(tn & 1) * (BB * HH) + (size_t)m * HH + k;
                    float4 a  = *(const float4*)(s);
                    float4 b  = *(const float4*)(s + 4);
                    float4 c2 = *(const float4*)(s + 8);
                    float4 e  = *(const float4*)(s + 12);
                    f16x8 r0, r1;
                    r0[0]=(f16)a.x;  r0[1]=(f16)a.y;  r0[2]=(f16)a.z;  r0[3]=(f16)a.w;
                    r0[4]=(f16)b.x;  r0[5]=(f16)b.y;  r0[6]=(f16)b.z;  r0[7]=(f16)b.w;
                    r1[0]=(f16)c2.x; r1[1]=(f16)c2.y; r1[2]=(f16)c2.z; r1[3]=(f16)c2.w;
                    r1[4]=(f16)e.x;  r1[5]=(f16)e.y;  r1[6]=(f16)e.z;  r1[7]=(f16)e.w;
                    *(f16x8*)(dd) = r0;
                    *(f16x8*)(dd + 8) = r1;
                }
            }
            gsync(P.barc, P.barg);
        }
    }
}

// ---------------------------------------------------------------------------
// Host side
// ---------------------------------------------------------------------------
extern "C" void kernel_launch(void* const* d_in, const int* in_sizes, int n_in,
                              void* d_out, int out_size, void* d_ws, size_t ws_size,
                              hipStream_t stream)
{
    (void)in_sizes; (void)n_in; (void)out_size; (void)ws_size;

    const float* H0in  = (const float*)d_in[0];
    const float* lin_w = (const float*)d_in[1];
    const float* lin_b = (const float*)d_in[2];
    const float* g0_w  = (const float*)d_in[3];
    const float* g0_b  = (const float*)d_in[4];
    const float* g1_w  = (const float*)d_in[5];
    const float* g1_b  = (const float*)d_in[6];

    float* H0out = (float*)d_out;                       // (B,T,H)
    float* H1st  = H0out + (size_t)BB * TT * HH;        // (B,L,H)

    // Workspace layout (~58 MB)
    char* p = (char*)d_ws;
    f16* linT = (f16*)p;  p += (size_t)LL * JJ * 2048 * 1024 * sizeof(f16); // 32 MB
    f16* g0T  = (f16*)p;  p += (size_t)LL * JJ * 512 * 1024 * sizeof(f16);  //  8 MB
    f16* g1T  = (f16*)p;  p += (size_t)LL * JJ * 512 * 1024 * sizeof(f16);  //  8 MB
    f16* h1f16 = (f16*)p; p += (size_t)LL * BB * HH * sizeof(f16);
    float* pipe32 = (float*)p; p += (size_t)2 * LL * BB * HH * sizeof(float);
    f16* pipe16 = (f16*)p;     p += (size_t)2 * LL * BB * HH * sizeof(f16);
    float* h0m32 = (float*)p;  p += (size_t)LL * BB * HH * sizeof(float);
    f16* h0m16 = (f16*)p;      p += (size_t)LL * BB * HH * sizeof(f16);
    float* h1m32 = (float*)p;  p += (size_t)LL * BB * HH * sizeof(float);
    f16* h1m16 = (f16*)p;      p += (size_t)LL * BB * HH * sizeof(f16);
    f16* a0hi = (f16*)p;       p += (size_t)LL * BB * HH * sizeof(f16);
    f16* a1hi = (f16*)p;       p += (size_t)LL * BB * HH * sizeof(f16);
    float* z0b = (float*)p;    p += (size_t)LL * BB * HH * sizeof(float);
    float* z1b = (float*)p;    p += (size_t)LL * BB * HH * sizeof(float);
    f16* h0c = (f16*)p;        p += (size_t)2 * BB * HH * sizeof(f16);
    unsigned* barc = (unsigned*)p; p += 128;
    unsigned* barg = (unsigned*)p; p += 128;

    // One-time (per call) weight fp16 transposes
    wt_transpose_cvt<<<dim3(32, 64, 8), 256, 0, stream>>>(lin_w, linT, 1024, 2048);
    wt_transpose_cvt<<<dim3(32, 16, 8), 256, 0, stream>>>(g0_w,  g0T,  1024, 512);
    wt_transpose_cvt<<<dim3(32, 16, 8), 256, 0, stream>>>(g1_w,  g1T,  1024, 512);
    hipMemsetAsync(H1st, 0, (size_t)BB * LL * HH * sizeof(float), stream);
    hipMemsetAsync(barc, 0, 256, stream);   // covers barc + barg

    PK P;
    P.H0in = H0in; P.lin_b = lin_b; P.g0_b = g0_b; P.g1_b = g1_b;
    P.linT = linT; P.g0T = g0T; P.g1T = g1T;
    P.H0out = H0out; P.H1st = H1st;
    P.h1f16 = h1f16; P.pipe32 = pipe32; P.pipe16 = pipe16;
    P.h0m32 = h0m32; P.h0m16 = h0m16; P.h1m32 = h1m32; P.h1m16 = h1m16;
    P.a0hi = a0hi; P.a1hi = a1hi; P.z0 = z0b; P.z1 = z1b;
    P.h0c = h0c; P.barc = barc; P.barg = barg;

    lattice_persistent<<<dim3(NBLK), 256, 0, stream>>>(P);
}

// Round 3
// 51645.776 us; speedup vs baseline: 1.1088x; 1.0224x over previous
//
#include <hip/hip_runtime.h>

// Problem constants
#define HH 512
#define BB 128
#define TT 512
#define LL 4
#define JJ 2
#define NBLK 256   // persistent grid size (cooperative launch => co-resident)
#define GRPS 8
#define GRPSZ (NBLK / GRPS)
#define SPIN_LIMIT 200000   // ~30 ms; legit waits are <20 us

typedef _Float16 f16;
typedef __attribute__((ext_vector_type(4))) _Float16 f16x4;
typedef __attribute__((ext_vector_type(8))) _Float16 f16x8;
typedef __attribute__((ext_vector_type(4))) float f32x4;

// ---------------------------------------------------------------------------
// Weight convert + transpose: src fp32 [mat][K][N] -> dst fp16 [mat][N][K]
// ---------------------------------------------------------------------------
__global__ __launch_bounds__(256) void wt_transpose_cvt(
    const float* __restrict__ src, f16* __restrict__ dst, int K, int N)
{
    __shared__ f16 tile[32][33];
    const size_t mat = blockIdx.z;
    const float* s = src + mat * (size_t)K * N;
    f16* d = dst + mat * (size_t)K * N;
    const int k0 = blockIdx.x * 32, n0 = blockIdx.y * 32;
    const int tx = threadIdx.x & 31, ty = threadIdx.x >> 5; // 32 x 8
#pragma unroll
    for (int i = 0; i < 4; i++) {
        int k = k0 + ty + 8 * i;
        tile[ty + 8 * i][tx] = (f16)s[(size_t)k * N + n0 + tx];
    }
    __syncthreads();
#pragma unroll
    for (int i = 0; i < 4; i++) {
        int n = n0 + ty + 8 * i;
        d[(size_t)n * K + k0 + tx] = tile[tx][ty + 8 * i];
    }
}

// ---------------------------------------------------------------------------
// Persistent-kernel parameter block
// ---------------------------------------------------------------------------
struct PK {
    const float* H0in;
    const float* lin_b;
    const float* g0_b;
    const float* g1_b;
    const f16* linT;   // [L][J][2048][1024]
    const f16* g0T;    // [L][J][512][1024]
    const f16* g1T;
    float* H0out;      // (B,T,H)
    float* H1st;       // (B,L,H) f32 state, lives in d_out
    f16*   h1f16;      // [L][B][H] fp16 mirror of H1st
    float* pipe32;     // [2][L][B][H] h0 between layers (parity d&1)
    f16*   pipe16;
    float* h0m32; f16* h0m16;   // [L][B][H] j-intermediate h0
    float* h1m32; f16* h1m16;   // [L][B][H] j-intermediate h1
    f16* a0hi; f16* a1hi;       // [L][B][H] gated halves h1*r, h0*q
    float* z0; float* z1;       // [L][B][H] gates
    f16* h0c;                   // [2][B][H] fp16 of H0in[:,t,:] (parity t&1)
    unsigned* bar;              // barrier block
};

// Two-level device-scope grid barrier. Layout (uint index):
//   bar[0]   = generation
//   bar[32]  = root counter
//   bar[64 + g*32] = group-g counter (g = bid & 7), separate cachelines
//   bar[352] = broken flag (spin timeout => degrade to no-op, finish wrong
//              but FINISH -- converts a residency bug into an absmax report)
__device__ inline void gsync(unsigned* bar, int bid)
{
    __syncthreads();
    if (threadIdx.x == 0) {
        unsigned* gen  = bar;
        unsigned* root = bar + 32;
        unsigned* gcnt = bar + 64 + (bid & (GRPS - 1)) * 32;
        unsigned* brk  = bar + 352;
        if (__hip_atomic_load(brk, __ATOMIC_RELAXED, __HIP_MEMORY_SCOPE_AGENT) == 0u) {
            __threadfence();  // release this block's writes device-wide
            unsigned g = __hip_atomic_load(gen, __ATOMIC_RELAXED, __HIP_MEMORY_SCOPE_AGENT);
            unsigned prev = __hip_atomic_fetch_add(gcnt, 1u, __ATOMIC_RELAXED, __HIP_MEMORY_SCOPE_AGENT);
            if (prev == GRPSZ - 1) {
                __hip_atomic_store(gcnt, 0u, __ATOMIC_RELAXED, __HIP_MEMORY_SCOPE_AGENT);
                __threadfence();  // order reset before root bump
                unsigned r = __hip_atomic_fetch_add(root, 1u, __ATOMIC_RELAXED, __HIP_MEMORY_SCOPE_AGENT);
                if (r == GRPS - 1) {
                    __hip_atomic_store(root, 0u, __ATOMIC_RELAXED, __HIP_MEMORY_SCOPE_AGENT);
                    __threadfence();  // order root reset before release
                    __hip_atomic_store(gen, g + 1u, __ATOMIC_RELAXED, __HIP_MEMORY_SCOPE_AGENT);
                }
            }
            unsigned spins = 0;
            while (__hip_atomic_load(gen, __ATOMIC_RELAXED, __HIP_MEMORY_SCOPE_AGENT) == g) {
                __builtin_amdgcn_s_sleep(1);
                if (++spins > SPIN_LIMIT) {
                    __hip_atomic_store(brk, 1u, __ATOMIC_RELAXED, __HIP_MEMORY_SCOPE_AGENT);
                    break;
                }
                if (__hip_atomic_load(brk, __ATOMIC_RELAXED, __HIP_MEMORY_SCOPE_AGENT) != 0u)
                    break;
            }
        }
        __threadfence();  // acquire before reading others' data
    }
    __syncthreads();
}

// ---------------------------------------------------------------------------
// Stage 1 tile: g = sigmoid([h0|h1] @ lin_w + b). M=128, N=32 (BN=32), K=1024.
// Software-pipelined: double-buffered LDS, global->reg prefetch overlaps MFMA,
// ONE __syncthreads per K-step.
// 4 waves: wm = wid&1 (64-row half), wn = wid>>1 (16-col half). acc[4] frags.
// Epilogue by column class: 0 -> z0, 1 -> z1, 2 -> a0hi = h1*r, 3 -> a1hi = h0*q
// ---------------------------------------------------------------------------
__device__ __forceinline__ void s1_tile(
    const f16* __restrict__ alo, const f16* __restrict__ ahi,
    const f16* __restrict__ wT, const float* __restrict__ bias,
    float* __restrict__ z0, float* __restrict__ z1,
    f16* __restrict__ a0hi, f16* __restrict__ a1hi,
    int n0, int tid, int lane, int wid,
    f16 (*Al)[72], f16 (*Bl)[72])
{
    const int wm = wid & 1;
    const int wn = wid >> 1;
    const int kc = tid & 7;   // 8 k-groups of 8 halves = 64 k
    const int rb = tid >> 3;  // 32-row base
    f32x4 acc[4] = {};
    f16x8 ra0, ra1, ra2, ra3, rbv;

    auto LOAD = [&](int K0) {
        const f16* ab = (K0 < 512 ? alo : ahi) + (K0 & 511) + kc * 8;
        ra0 = *(const f16x8*)(ab + (size_t)(rb)      * 512);
        ra1 = *(const f16x8*)(ab + (size_t)(rb + 32) * 512);
        ra2 = *(const f16x8*)(ab + (size_t)(rb + 64) * 512);
        ra3 = *(const f16x8*)(ab + (size_t)(rb + 96) * 512);
        rbv = *(const f16x8*)(wT + (size_t)(n0 + rb) * 1024 + K0 + kc * 8);
    };
    auto WRITE = [&](int buf) {
        *(f16x8*)(&Al[buf * 128 + rb     ][kc * 8]) = ra0;
        *(f16x8*)(&Al[buf * 128 + rb + 32][kc * 8]) = ra1;
        *(f16x8*)(&Al[buf * 128 + rb + 64][kc * 8]) = ra2;
        *(f16x8*)(&Al[buf * 128 + rb + 96][kc * 8]) = ra3;
        *(f16x8*)(&Bl[buf * 32 + rb][kc * 8]) = rbv;
    };

    LOAD(0);
    WRITE(0);
    __syncthreads();
#pragma unroll
    for (int it = 0; it < 16; ++it) {
        const int cur = it & 1;
        if (it < 15) LOAD((it + 1) * 64);   // prefetch overlaps compute below
#pragma unroll
        for (int ks = 0; ks < 2; ++ks) {
            const int kl = ks * 32 + (lane >> 4) * 8;
            f16x8 bf = *(const f16x8*)(&Bl[cur * 32 + wn * 16 + (lane & 15)][kl]);
#pragma unroll
            for (int fm = 0; fm < 4; fm++) {
                f16x8 af = *(const f16x8*)(&Al[cur * 128 + wm * 64 + fm * 16 + (lane & 15)][kl]);
                acc[fm] = __builtin_amdgcn_mfma_f32_16x16x32_f16(af, bf, acc[fm], 0, 0, 0);
            }
        }
        if (it < 15) { WRITE(cur ^ 1); __syncthreads(); }
    }

    const int cls = n0 >> 9;
#pragma unroll
    for (int fm = 0; fm < 4; fm++) {
#pragma unroll
        for (int r = 0; r < 4; r++) {
            int m = wm * 64 + fm * 16 + (lane >> 4) * 4 + r;
            int n = n0 + wn * 16 + (lane & 15);
            float x = acc[fm][r] + bias[n];
            float s = 1.0f / (1.0f + __expf(-x));
            int nn = n & 511;
            if (cls == 0)      z0[m * 512 + nn] = s;
            else if (cls == 1) z1[m * 512 + nn] = s;
            else if (cls == 2) a0hi[m * 512 + nn] = (f16)((float)ahi[m * 512 + nn] * s);
            else               a1hi[m * 512 + nn] = (f16)((float)alo[m * 512 + nn] * s);
        }
    }
}

// ---------------------------------------------------------------------------
// Stage 2 tile: hc = tanh(A @ gw + gb); dst = z*hc + (1-z)*old.
// M=128, N=16 (BN=16), K=1024, pipelined like s1.
// 4 waves split M 4-way (32 rows each), acc[2] frags, all waves share B frag.
// ---------------------------------------------------------------------------
__device__ __forceinline__ void s2_tile(
    const f16* __restrict__ alo, const f16* __restrict__ ahi,
    const f16* __restrict__ wT, const float* __restrict__ bias,
    const float* __restrict__ zg, const float* __restrict__ oldp, int olds,
    float* __restrict__ dst32, int dsts, f16* __restrict__ dst16,
    int n0, int tid, int lane, int wid,
    f16 (*Al)[72], f16 (*Bl)[72])
{
    const int kc  = tid & 7;
    const int rb  = tid >> 3;
    const int kc2 = tid & 15;  // 16 k-groups of 4 halves = 64 k
    const int rb2 = tid >> 4;  // 16 rows
    f32x4 acc[2] = {};
    f16x8 ra0, ra1, ra2, ra3;
    f16x4 rbv;

    auto LOAD = [&](int K0) {
        const f16* ab = (K0 < 512 ? alo : ahi) + (K0 & 511) + kc * 8;
        ra0 = *(const f16x8*)(ab + (size_t)(rb)      * 512);
        ra1 = *(const f16x8*)(ab + (size_t)(rb + 32) * 512);
        ra2 = *(const f16x8*)(ab + (size_t)(rb + 64) * 512);
        ra3 = *(const f16x8*)(ab + (size_t)(rb + 96) * 512);
        rbv = *(const f16x4*)(wT + (size_t)(n0 + rb2) * 1024 + K0 + kc2 * 4);
    };
    auto WRITE = [&](int buf) {
        *(f16x8*)(&Al[buf * 128 + rb     ][kc * 8]) = ra0;
        *(f16x8*)(&Al[buf * 128 + rb + 32][kc * 8]) = ra1;
        *(f16x8*)(&Al[buf * 128 + rb + 64][kc * 8]) = ra2;
        *(f16x8*)(&Al[buf * 128 + rb + 96][kc * 8]) = ra3;
        *(f16x4*)(&Bl[buf * 16 + rb2][kc2 * 4]) = rbv;
    };

    LOAD(0);
    WRITE(0);
    __syncthreads();
#pragma unroll
    for (int it = 0; it < 16; ++it) {
        const int cur = it & 1;
        if (it < 15) LOAD((it + 1) * 64);
#pragma unroll
        for (int ks = 0; ks < 2; ++ks) {
            const int kl = ks * 32 + (lane >> 4) * 8;
            f16x8 bf = *(const f16x8*)(&Bl[cur * 16 + (lane & 15)][kl]);
#pragma unroll
            for (int fm = 0; fm < 2; fm++) {
                f16x8 af = *(const f16x8*)(&Al[cur * 128 + wid * 32 + fm * 16 + (lane & 15)][kl]);
                acc[fm] = __builtin_amdgcn_mfma_f32_16x16x32_f16(af, bf, acc[fm], 0, 0, 0);
            }
        }
        if (it < 15) { WRITE(cur ^ 1); __syncthreads(); }
    }

#pragma unroll
    for (int fm = 0; fm < 2; fm++) {
#pragma unroll
        for (int r = 0; r < 4; r++) {
            int m = wid * 32 + fm * 16 + (lane >> 4) * 4 + r;
            int n = n0 + (lane & 15);
            float hc  = tanhf(acc[fm][r] + bias[n]);
            float zv  = zg[m * 512 + n];
            float old = oldp[(size_t)m * olds + n];
            float v = zv * hc + (1.0f - zv) * old;
            dst32[(size_t)m * dsts + n] = v;
            if (dst16) dst16[m * 512 + n] = (f16)v;
        }
    }
}

// ---------------------------------------------------------------------------
// Persistent kernel: whole wavefront in one launch, phases split across all
// 256 CUs (s1: nc*64 tiles BN=32; s2: nc*64 tiles BN=16), two-level barrier.
// ---------------------------------------------------------------------------
__global__ __launch_bounds__(256, 1) void lattice_persistent(PK P)
{
    __shared__ __attribute__((aligned(16))) f16 Al[2 * 128][72];
    __shared__ __attribute__((aligned(16))) f16 Bl[2 * 32][72];

    const int tid  = threadIdx.x;
    const int lane = tid & 63;
    const int wid  = tid >> 6;
    const int bid  = blockIdx.x;

    // ---- prologue: zero h1 fp16 mirror; convert H0in[:,0,:] -> h0c[0]
    {
        int g = bid * 256 + tid;                 // 0..65535
        if (g < 32768) {
            f16x8 zz = {};
            ((f16x8*)P.h1f16)[g] = zz;           // 32768 vectors exactly
        }
        int m = g >> 9;
        int k = g & 511;
        P.h0c[(size_t)m * HH + k] = (f16)P.H0in[(size_t)m * (TT * HH) + k];
    }
    gsync(P.bar, bid);

    for (int d = 0; d < TT + LL - 1; ++d) {
        int lmin = d - (TT - 1); if (lmin < 0) lmin = 0;
        int lmax = d < LL - 1 ? d : LL - 1;
        int nc = lmax - lmin + 1;
        for (int j = 0; j < JJ; ++j) {
            // ================= stage 1 phase: nc*64 tiles (BN=32) ==========
            int nt1 = nc * 64;
            for (int tile = bid; tile < nt1; tile += NBLK) {
                int l = lmin + (tile >> 6);
                int n0 = (tile & 63) * 32;
                int w = l * JJ + j;
                const f16 *alo, *ahi;
                if (j == 0) {
                    alo = (l == 0) ? P.h0c + (size_t)(d & 1) * (BB * HH)
                                   : P.pipe16 + (size_t)((d & 1) * LL + l) * (BB * HH);
                    ahi = P.h1f16 + (size_t)l * (BB * HH);
                } else {
                    alo = P.h0m16 + (size_t)l * (BB * HH);
                    ahi = P.h1m16 + (size_t)l * (BB * HH);
                }
                s1_tile(alo, ahi,
                        P.linT + (size_t)w * (2048 * 1024),
                        P.lin_b + (size_t)w * 2048,
                        P.z0 + (size_t)l * (BB * HH), P.z1 + (size_t)l * (BB * HH),
                        P.a0hi + (size_t)l * (BB * HH), P.a1hi + (size_t)l * (BB * HH),
                        n0, tid, lane, wid, Al, Bl);
            }
            gsync(P.bar, bid);

            // ========== stage 2 phase: nc*64 tiles BN=16 (+16 conv) ========
            int nt2 = nc * 64;
            bool cv = (j == 1) && (d + 1 < TT);
            int ntt = nt2 + (cv ? 16 : 0);
            for (int tile = bid; tile < ntt; tile += NBLK) {
                if (tile < nt2) {
                    int ci = tile >> 6;
                    int rem = tile & 63;
                    int gi = rem >> 5;          // 0: g0 (-> new h1), 1: g1 (-> new h0)
                    int n0 = (rem & 31) * 16;
                    int l = lmin + ci, t = d - l;
                    int w = l * JJ + j;
                    const f16 *alo, *ahi, *wTp;
                    const float *bp, *zp, *op;
                    int os, ds;
                    float* d32; f16* d16;
                    if (gi == 0) {
                        // g0: A=[h0 | h1*r] -> h0_cap; new h1 = z1*hc + (1-z1)*h1
                        if (j == 0) {
                            alo = (l == 0) ? P.h0c + (size_t)(d & 1) * (BB * HH)
                                           : P.pipe16 + (size_t)((d & 1) * LL + l) * (BB * HH);
                            op = P.H1st + (size_t)l * HH; os = LL * HH;
                            d32 = P.h1m32 + (size_t)l * (BB * HH); ds = HH;
                            d16 = P.h1m16 + (size_t)l * (BB * HH);
                        } else {
                            alo = P.h0m16 + (size_t)l * (BB * HH);
                            op = P.h1m32 + (size_t)l * (BB * HH); os = HH;
                            d32 = P.H1st + (size_t)l * HH; ds = LL * HH;
                            d16 = P.h1f16 + (size_t)l * (BB * HH);
                        }
                        ahi = P.a0hi + (size_t)l * (BB * HH);
                        wTp = P.g0T + (size_t)w * (512 * 1024);
                        bp  = P.g0_b + (size_t)w * 512;
                        zp  = P.z1 + (size_t)l * (BB * HH);
                    } else {
                        // g1: A=[h1 | h0*q] -> h1_cap; new h0 = z0*hc + (1-z0)*h0
                        if (j == 0) {
                            alo = P.h1f16 + (size_t)l * (BB * HH);
                            op = (l == 0) ? P.H0in + (size_t)t * HH
                                          : P.pipe32 + (size_t)((d & 1) * LL + l) * (BB * HH);
                            os = (l == 0) ? (TT * HH) : HH;
                            d32 = P.h0m32 + (size_t)l * (BB * HH); ds = HH;
                            d16 = P.h0m16 + (size_t)l * (BB * HH);
                        } else {
                            alo = P.h1m16 + (size_t)l * (BB * HH);
                            op = P.h0m32 + (size_t)l * (BB * HH); os = HH;
                            if (l == LL - 1) {
                                d32 = P.H0out + (size_t)t * HH; ds = TT * HH; d16 = nullptr;
                            } else {
                                d32 = P.pipe32 + (size_t)(((d + 1) & 1) * LL + (l + 1)) * (BB * HH); ds = HH;
                                d16 = P.pipe16 + (size_t)(((d + 1) & 1) * LL + (l + 1)) * (BB * HH);
                            }
                        }
                        ahi = P.a1hi + (size_t)l * (BB * HH);
                        wTp = P.g1T + (size_t)w * (512 * 1024);
                        bp  = P.g1_b + (size_t)w * 512;
                        zp  = P.z0 + (size_t)l * (BB * HH);
                    }
                    s2_tile(alo, ahi, wTp, bp, zp, op, os, d32, ds, d16,
                            n0, tid, lane, wid, Al, Bl);
                } else {
                    // convert H0in[:, d+1, :] -> h0c[(d+1)&1] for next diagonal
                    int ct = tile - nt2;            // 0..15
                    int tn = d + 1;
                    int m = ct * 8 + (tid >> 5);
                    int k = (tid & 31) * 16;
                    const float* s = P.H0in + (size_t)m * (TT * HH) + (size_t)tn * HH + k;
                    f16* dd = P.h0c + (size_t)(tn & 1) * (BB * HH) + (size_t)m * HH + k;
                    float4 a  = *(const float4*)(s);
                    float4 b  = *(const float4*)(s + 4);
                    float4 c2 = *(const float4*)(s + 8);
                    float4 e  = *(const float4*)(s + 12);
                    f16x8 r0, r1;
                    r0[0]=(f16)a.x;  r0[1]=(f16)a.y;  r0[2]=(f16)a.z;  r0[3]=(f16)a.w;
                    r0[4]=(f16)b.x;  r0[5]=(f16)b.y;  r0[6]=(f16)b.z;  r0[7]=(f16)b.w;
                    r1[0]=(f16)c2.x; r1[1]=(f16)c2.y; r1[2]=(f16)c2.z; r1[3]=(f16)c2.w;
                    r1[4]=(f16)e.x;  r1[5]=(f16)e.y;  r1[6]=(f16)e.z;  r1[7]=(f16)e.w;
                    *(f16x8*)(dd) = r0;
                    *(f16x8*)(dd + 8) = r1;
                }
            }
            gsync(P.bar, bid);
        }
    }
}

// ---------------------------------------------------------------------------
// Host side
// ---------------------------------------------------------------------------
extern "C" void kernel_launch(void* const* d_in, const int* in_sizes, int n_in,
                              void* d_out, int out_size, void* d_ws, size_t ws_size,
                              hipStream_t stream)
{
    (void)in_sizes; (void)n_in; (void)out_size; (void)ws_size;

    const float* H0in  = (const float*)d_in[0];
    const float* lin_w = (const float*)d_in[1];
    const float* lin_b = (const float*)d_in[2];
    const float* g0_w  = (const float*)d_in[3];
    const float* g0_b  = (const float*)d_in[4];
    const float* g1_w  = (const float*)d_in[5];
    const float* g1_b  = (const float*)d_in[6];

    float* H0out = (float*)d_out;                       // (B,T,H)
    float* H1st  = H0out + (size_t)BB * TT * HH;        // (B,L,H)

    // Workspace layout (~58 MB)
    char* p = (char*)d_ws;
    f16* linT = (f16*)p;  p += (size_t)LL * JJ * 2048 * 1024 * sizeof(f16); // 32 MB
    f16* g0T  = (f16*)p;  p += (size_t)LL * JJ * 512 * 1024 * sizeof(f16);  //  8 MB
    f16* g1T  = (f16*)p;  p += (size_t)LL * JJ * 512 * 1024 * sizeof(f16);  //  8 MB
    f16* h1f16 = (f16*)p; p += (size_t)LL * BB * HH * sizeof(f16);
    float* pipe32 = (float*)p; p += (size_t)2 * LL * BB * HH * sizeof(float);
    f16* pipe16 = (f16*)p;     p += (size_t)2 * LL * BB * HH * sizeof(f16);
    float* h0m32 = (float*)p;  p += (size_t)LL * BB * HH * sizeof(float);
    f16* h0m16 = (f16*)p;      p += (size_t)LL * BB * HH * sizeof(f16);
    float* h1m32 = (float*)p;  p += (size_t)LL * BB * HH * sizeof(float);
    f16* h1m16 = (f16*)p;      p += (size_t)LL * BB * HH * sizeof(f16);
    f16* a0hi = (f16*)p;       p += (size_t)LL * BB * HH * sizeof(f16);
    f16* a1hi = (f16*)p;       p += (size_t)LL * BB * HH * sizeof(f16);
    float* z0b = (float*)p;    p += (size_t)LL * BB * HH * sizeof(float);
    float* z1b = (float*)p;    p += (size_t)LL * BB * HH * sizeof(float);
    f16* h0c = (f16*)p;        p += (size_t)2 * BB * HH * sizeof(f16);
    unsigned* bar = (unsigned*)p; p += 4096;

    // One-time (per call) weight fp16 transposes
    wt_transpose_cvt<<<dim3(32, 64, 8), 256, 0, stream>>>(lin_w, linT, 1024, 2048);
    wt_transpose_cvt<<<dim3(32, 16, 8), 256, 0, stream>>>(g0_w,  g0T,  1024, 512);
    wt_transpose_cvt<<<dim3(32, 16, 8), 256, 0, stream>>>(g1_w,  g1T,  1024, 512);
    hipMemsetAsync(H1st, 0, (size_t)BB * LL * HH * sizeof(float), stream);
    hipMemsetAsync(bar, 0, 4096, stream);

    PK P;
    P.H0in = H0in; P.lin_b = lin_b; P.g0_b = g0_b; P.g1_b = g1_b;
    P.linT = linT; P.g0T = g0T; P.g1T = g1T;
    P.H0out = H0out; P.H1st = H1st;
    P.h1f16 = h1f16; P.pipe32 = pipe32; P.pipe16 = pipe16;
    P.h0m32 = h0m32; P.h0m16 = h0m16; P.h1m32 = h1m32; P.h1m16 = h1m16;
    P.a0hi = a0hi; P.a1hi = a1hi; P.z0 = z0b; P.z1 = z1b;
    P.h0c = h0c; P.bar = bar;

    // Cooperative launch: runtime guarantees all NBLK blocks are co-resident
    // (or fails cleanly). Fallback to plain launch if coop is unavailable.
    void* args[] = { (void*)&P };
    hipError_t e = hipLaunchCooperativeKernel((const void*)lattice_persistent,
                                              dim3(NBLK), dim3(256), args, 0, stream);
    if (e != hipSuccess) {
        lattice_persistent<<<dim3(NBLK), 256, 0, stream>>>(P);
    }
}

// Round 4
// 36885.349 us; speedup vs baseline: 1.5525x; 1.4002x over previous
//
#include <hip/hip_runtime.h>

// Problem constants
#define HH 512
#define BB 128
#define TT 512
#define LL 4
#define JJ 2
#define NBLK 256   // persistent grid size (cooperative launch => co-resident)
#define SPIN_LIMIT 50000

typedef _Float16 f16;
typedef __attribute__((ext_vector_type(4))) _Float16 f16x4;
typedef __attribute__((ext_vector_type(8))) _Float16 f16x8;
typedef __attribute__((ext_vector_type(4))) float f32x4;

#define AR __ATOMIC_RELAXED
#define AS __HIP_MEMORY_SCOPE_AGENT

// ---------------------------------------------------------------------------
// Agent-scope (sc0 sc1: L1+L2 bypass, coherent at L3) access helpers.
// Used for ALL mutable cross-block data. Weights/bias/H0in use normal cached
// loads and stay L2-resident (no more buffer_inv nuking them every phase).
// ---------------------------------------------------------------------------
__device__ __forceinline__ f16x8 ald16(const f16* p) {
    union { unsigned long long u[2]; f16x8 v; } r;
    const unsigned long long* q = (const unsigned long long*)p;
    r.u[0] = __hip_atomic_load(q, AR, AS);
    r.u[1] = __hip_atomic_load(q + 1, AR, AS);
    return r.v;
}
__device__ __forceinline__ void ast16(f16* p, f16x8 v) {
    union { f16x8 v; unsigned long long u[2]; } r; r.v = v;
    unsigned long long* q = (unsigned long long*)p;
    __hip_atomic_store(q, r.u[0], AR, AS);
    __hip_atomic_store(q + 1, r.u[1], AR, AS);
}
__device__ __forceinline__ float aldf(const float* p) { return __hip_atomic_load(p, AR, AS); }
__device__ __forceinline__ void astf(float* p, float v) { __hip_atomic_store(p, v, AR, AS); }
__device__ __forceinline__ f16 aldh(const f16* p) {
    unsigned short u = __hip_atomic_load((const unsigned short*)p, AR, AS);
    union { unsigned short s; f16 h; } c; c.s = u; return c.h;
}
__device__ __forceinline__ void asth(f16* p, f16 v) {
    union { f16 h; unsigned short s; } c; c.h = v;
    __hip_atomic_store((unsigned short*)p, c.s, AR, AS);
}

// ---------------------------------------------------------------------------
// Weight convert + transpose: src fp32 [mat][K][N] -> dst fp16 [mat][N][K]
// ---------------------------------------------------------------------------
__global__ __launch_bounds__(256) void wt_transpose_cvt(
    const float* __restrict__ src, f16* __restrict__ dst, int K, int N)
{
    __shared__ f16 tile[32][33];
    const size_t mat = blockIdx.z;
    const float* s = src + mat * (size_t)K * N;
    f16* d = dst + mat * (size_t)K * N;
    const int k0 = blockIdx.x * 32, n0 = blockIdx.y * 32;
    const int tx = threadIdx.x & 31, ty = threadIdx.x >> 5; // 32 x 8
#pragma unroll
    for (int i = 0; i < 4; i++) {
        int k = k0 + ty + 8 * i;
        tile[ty + 8 * i][tx] = (f16)s[(size_t)k * N + n0 + tx];
    }
    __syncthreads();
#pragma unroll
    for (int i = 0; i < 4; i++) {
        int n = n0 + ty + 8 * i;
        d[(size_t)n * K + k0 + tx] = tile[tx][ty + 8 * i];
    }
}

// ---------------------------------------------------------------------------
// Persistent-kernel parameter block
// ---------------------------------------------------------------------------
struct PK {
    const float* H0in;
    const float* lin_b;
    const float* g0_b;
    const float* g1_b;
    const f16* linT;   // [L][J][2048][1024]
    const f16* g0T;    // [L][J][512][1024]
    const f16* g1T;
    float* H0out;      // (B,T,H)
    float* H1st;       // (B,L,H) f32 state, lives in d_out
    f16*   h1f16;      // [L][B][H] fp16 mirror of H1st
    float* pipe32;     // [2][L][B][H] h0 between layers (parity d&1)
    f16*   pipe16;
    float* h0m32; f16* h0m16;   // [L][B][H] j-intermediate h0
    float* h1m32; f16* h1m16;   // [L][B][H] j-intermediate h1
    f16* a0hi; f16* a1hi;       // [L][B][H] gated halves h1*r, h0*q
    float* z0; float* z1;       // [L][B][H] gates
    f16* h0c;                   // [2][B][H] fp16 of H0in[:,t,:] (parity t&1)
    unsigned* bar;              // barrier block
};

// Versioned two-level grid barrier, NO cache-maintenance fences.
//   bar[0]            = generation (monotonic)
//   bar[32]           = root counter (monotonic)
//   bar[64 + g*32]    = group-g counter (g = bid & 15), monotonic
//   bar[576]          = sticky broken flag
// Release: s_waitcnt vmcnt(0) before arrival => all this block's agent-scope
// stores have reached L3 (the coherence point). Acquire: consumer loads are
// agent-scope (L1/L2 bypass) and control-depend on the gen flip.
__device__ inline void gsync(unsigned* bar, int bid, unsigned ph)
{
    __syncthreads();
    if (threadIdx.x == 0) {
        unsigned* gen  = bar;
        unsigned* root = bar + 32;
        unsigned* gcnt = bar + 64 + (bid & 15) * 32;
        unsigned* brk  = bar + 576;
        if (__hip_atomic_load(brk, AR, AS) == 0u) {
            asm volatile("s_waitcnt vmcnt(0)" ::: "memory"); // release
            unsigned prev = __hip_atomic_fetch_add(gcnt, 1u, AR, AS);
            if (prev == ph * 16u + 15u) {                    // group leader
                unsigned r = __hip_atomic_fetch_add(root, 1u, AR, AS);
                if (r == ph * 16u + 15u) {                   // last group
                    __hip_atomic_store(gen, ph + 1u, AR, AS);
                }
            }
            unsigned spins = 0;
            while ((int)(__hip_atomic_load(gen, AR, AS) - (ph + 1u)) < 0) {
                __builtin_amdgcn_s_sleep(1);
                if (++spins > SPIN_LIMIT) {
                    __hip_atomic_store(brk, 1u, AR, AS);
                    break;
                }
                if (__hip_atomic_load(brk, AR, AS) != 0u) break;
            }
        }
        asm volatile("" ::: "memory");
    }
    __syncthreads();
}

// ---------------------------------------------------------------------------
// Stage 1 tile: g = sigmoid([h0|h1] @ lin_w + b). M=128, N=32 (BN=32), K=1024.
// Pipelined: double-buffered LDS, global->reg prefetch overlaps MFMA, one
// __syncthreads per K-step. A loads agent-scope; B (weights) normal (L2-hot).
// Epilogue by column class: 0 -> z0, 1 -> z1, 2 -> a0hi = h1*r, 3 -> a1hi = h0*q
// ---------------------------------------------------------------------------
__device__ __forceinline__ void s1_tile(
    const f16* __restrict__ alo, const f16* __restrict__ ahi,
    const f16* __restrict__ wT, const float* __restrict__ bias,
    float* __restrict__ z0, float* __restrict__ z1,
    f16* __restrict__ a0hi, f16* __restrict__ a1hi,
    int n0, int tid, int lane, int wid,
    f16 (*Al)[72], f16 (*Bl)[72])
{
    const int wm = wid & 1;
    const int wn = wid >> 1;
    const int kc = tid & 7;   // 8 k-groups of 8 halves = 64 k
    const int rb = tid >> 3;  // 32-row base
    f32x4 acc[4] = {};
    f16x8 ra0, ra1, ra2, ra3, rbv;

    auto LOAD = [&](int K0) {
        const f16* ab = (K0 < 512 ? alo : ahi) + (K0 & 511) + kc * 8;
        ra0 = ald16(ab + (size_t)(rb)      * 512);
        ra1 = ald16(ab + (size_t)(rb + 32) * 512);
        ra2 = ald16(ab + (size_t)(rb + 64) * 512);
        ra3 = ald16(ab + (size_t)(rb + 96) * 512);
        rbv = *(const f16x8*)(wT + (size_t)(n0 + rb) * 1024 + K0 + kc * 8);
    };
    auto WRITE = [&](int buf) {
        *(f16x8*)(&Al[buf * 128 + rb     ][kc * 8]) = ra0;
        *(f16x8*)(&Al[buf * 128 + rb + 32][kc * 8]) = ra1;
        *(f16x8*)(&Al[buf * 128 + rb + 64][kc * 8]) = ra2;
        *(f16x8*)(&Al[buf * 128 + rb + 96][kc * 8]) = ra3;
        *(f16x8*)(&Bl[buf * 32 + rb][kc * 8]) = rbv;
    };

    LOAD(0);
    WRITE(0);
    __syncthreads();
#pragma unroll
    for (int it = 0; it < 16; ++it) {
        const int cur = it & 1;
        if (it < 15) LOAD((it + 1) * 64);   // prefetch overlaps compute below
#pragma unroll
        for (int ks = 0; ks < 2; ++ks) {
            const int kl = ks * 32 + (lane >> 4) * 8;
            f16x8 bf = *(const f16x8*)(&Bl[cur * 32 + wn * 16 + (lane & 15)][kl]);
#pragma unroll
            for (int fm = 0; fm < 4; fm++) {
                f16x8 af = *(const f16x8*)(&Al[cur * 128 + wm * 64 + fm * 16 + (lane & 15)][kl]);
                acc[fm] = __builtin_amdgcn_mfma_f32_16x16x32_f16(af, bf, acc[fm], 0, 0, 0);
            }
        }
        if (it < 15) { WRITE(cur ^ 1); __syncthreads(); }
    }

    const int cls = n0 >> 9;
#pragma unroll
    for (int fm = 0; fm < 4; fm++) {
#pragma unroll
        for (int r = 0; r < 4; r++) {
            int m = wm * 64 + fm * 16 + (lane >> 4) * 4 + r;
            int n = n0 + wn * 16 + (lane & 15);
            float x = acc[fm][r] + bias[n];
            float s = 1.0f / (1.0f + __expf(-x));
            int nn = n & 511;
            if (cls == 0)      astf(z0 + m * 512 + nn, s);
            else if (cls == 1) astf(z1 + m * 512 + nn, s);
            else if (cls == 2) asth(a0hi + m * 512 + nn, (f16)((float)aldh(ahi + m * 512 + nn) * s));
            else               asth(a1hi + m * 512 + nn, (f16)((float)aldh(alo + m * 512 + nn) * s));
        }
    }
}

// ---------------------------------------------------------------------------
// Stage 2 tile: hc = tanh(A @ gw + gb); dst = z*hc + (1-z)*old.
// M=128, N=16 (BN=16), K=1024, pipelined like s1.
// 4 waves split M 4-way (32 rows each), acc[2] frags, all waves share B frag.
// ---------------------------------------------------------------------------
__device__ __forceinline__ void s2_tile(
    const f16* __restrict__ alo, const f16* __restrict__ ahi,
    const f16* __restrict__ wT, const float* __restrict__ bias,
    const float* __restrict__ zg, const float* __restrict__ oldp, int olds,
    float* __restrict__ dst32, int dsts, f16* __restrict__ dst16,
    int n0, int tid, int lane, int wid,
    f16 (*Al)[72], f16 (*Bl)[72])
{
    const int kc  = tid & 7;
    const int rb  = tid >> 3;
    const int kc2 = tid & 15;  // 16 k-groups of 4 halves = 64 k
    const int rb2 = tid >> 4;  // 16 rows
    f32x4 acc[2] = {};
    f16x8 ra0, ra1, ra2, ra3;
    f16x4 rbv;

    auto LOAD = [&](int K0) {
        const f16* ab = (K0 < 512 ? alo : ahi) + (K0 & 511) + kc * 8;
        ra0 = ald16(ab + (size_t)(rb)      * 512);
        ra1 = ald16(ab + (size_t)(rb + 32) * 512);
        ra2 = ald16(ab + (size_t)(rb + 64) * 512);
        ra3 = ald16(ab + (size_t)(rb + 96) * 512);
        rbv = *(const f16x4*)(wT + (size_t)(n0 + rb2) * 1024 + K0 + kc2 * 4);
    };
    auto WRITE = [&](int buf) {
        *(f16x8*)(&Al[buf * 128 + rb     ][kc * 8]) = ra0;
        *(f16x8*)(&Al[buf * 128 + rb + 32][kc * 8]) = ra1;
        *(f16x8*)(&Al[buf * 128 + rb + 64][kc * 8]) = ra2;
        *(f16x8*)(&Al[buf * 128 + rb + 96][kc * 8]) = ra3;
        *(f16x4*)(&Bl[buf * 16 + rb2][kc2 * 4]) = rbv;
    };

    LOAD(0);
    WRITE(0);
    __syncthreads();
#pragma unroll
    for (int it = 0; it < 16; ++it) {
        const int cur = it & 1;
        if (it < 15) LOAD((it + 1) * 64);
#pragma unroll
        for (int ks = 0; ks < 2; ++ks) {
            const int kl = ks * 32 + (lane >> 4) * 8;
            f16x8 bf = *(const f16x8*)(&Bl[cur * 16 + (lane & 15)][kl]);
#pragma unroll
            for (int fm = 0; fm < 2; fm++) {
                f16x8 af = *(const f16x8*)(&Al[cur * 128 + wid * 32 + fm * 16 + (lane & 15)][kl]);
                acc[fm] = __builtin_amdgcn_mfma_f32_16x16x32_f16(af, bf, acc[fm], 0, 0, 0);
            }
        }
        if (it < 15) { WRITE(cur ^ 1); __syncthreads(); }
    }

#pragma unroll
    for (int fm = 0; fm < 2; fm++) {
#pragma unroll
        for (int r = 0; r < 4; r++) {
            int m = wid * 32 + fm * 16 + (lane >> 4) * 4 + r;
            int n = n0 + (lane & 15);
            float hc  = tanhf(acc[fm][r] + bias[n]);
            float zv  = aldf(zg + m * 512 + n);
            float old = aldf(oldp + (size_t)m * olds + n);
            float v = zv * hc + (1.0f - zv) * old;
            astf(dst32 + (size_t)m * dsts + n, v);
            if (dst16) asth(dst16 + m * 512 + n, (f16)v);
        }
    }
}

// ---------------------------------------------------------------------------
// Persistent kernel: whole wavefront in one launch, phases split across all
// 256 CUs (s1: nc*64 tiles BN=32; s2: nc*64 tiles BN=16), versioned barrier.
// ---------------------------------------------------------------------------
__global__ __launch_bounds__(256, 1) void lattice_persistent(PK P)
{
    __shared__ __attribute__((aligned(16))) f16 Al[2 * 128][72];
    __shared__ __attribute__((aligned(16))) f16 Bl[2 * 32][72];

    const int tid  = threadIdx.x;
    const int lane = tid & 63;
    const int wid  = tid >> 6;
    const int bid  = blockIdx.x;
    unsigned ph = 0;

    // ---- prologue: zero h1 fp16 mirror; convert H0in[:,0,:] -> h0c[0]
    {
        int g = bid * 256 + tid;                 // 0..65535
        if (g < 32768) {
            f16x8 zz = {};
            ast16(P.h1f16 + (size_t)g * 8, zz);  // 32768 vectors exactly
        }
        int m = g >> 9;
        int k = g & 511;
        asth(P.h0c + (size_t)m * HH + k, (f16)P.H0in[(size_t)m * (TT * HH) + k]);
    }
    gsync(P.bar, bid, ph++);

    for (int d = 0; d < TT + LL - 1; ++d) {
        int lmin = d - (TT - 1); if (lmin < 0) lmin = 0;
        int lmax = d < LL - 1 ? d : LL - 1;
        int nc = lmax - lmin + 1;
        for (int j = 0; j < JJ; ++j) {
            // ================= stage 1 phase: nc*64 tiles (BN=32) ==========
            int nt1 = nc * 64;
            for (int tile = bid; tile < nt1; tile += NBLK) {
                int l = lmin + (tile >> 6);
                int n0 = (tile & 63) * 32;
                int w = l * JJ + j;
                const f16 *alo, *ahi;
                if (j == 0) {
                    alo = (l == 0) ? P.h0c + (size_t)(d & 1) * (BB * HH)
                                   : P.pipe16 + (size_t)((d & 1) * LL + l) * (BB * HH);
                    ahi = P.h1f16 + (size_t)l * (BB * HH);
                } else {
                    alo = P.h0m16 + (size_t)l * (BB * HH);
                    ahi = P.h1m16 + (size_t)l * (BB * HH);
                }
                s1_tile(alo, ahi,
                        P.linT + (size_t)w * (2048 * 1024),
                        P.lin_b + (size_t)w * 2048,
                        P.z0 + (size_t)l * (BB * HH), P.z1 + (size_t)l * (BB * HH),
                        P.a0hi + (size_t)l * (BB * HH), P.a1hi + (size_t)l * (BB * HH),
                        n0, tid, lane, wid, Al, Bl);
            }
            gsync(P.bar, bid, ph++);

            // ========== stage 2 phase: nc*64 tiles BN=16 (+16 conv) ========
            int nt2 = nc * 64;
            bool cv = (j == 1) && (d + 1 < TT);
            int ntt = nt2 + (cv ? 16 : 0);
            for (int tile = bid; tile < ntt; tile += NBLK) {
                if (tile < nt2) {
                    int ci = tile >> 6;
                    int rem = tile & 63;
                    int gi = rem >> 5;          // 0: g0 (-> new h1), 1: g1 (-> new h0)
                    int n0 = (rem & 31) * 16;
                    int l = lmin + ci, t = d - l;
                    int w = l * JJ + j;
                    const f16 *alo, *ahi, *wTp;
                    const float *bp, *zp, *op;
                    int os, ds;
                    float* d32; f16* d16;
                    if (gi == 0) {
                        // g0: A=[h0 | h1*r] -> h0_cap; new h1 = z1*hc + (1-z1)*h1
                        if (j == 0) {
                            alo = (l == 0) ? P.h0c + (size_t)(d & 1) * (BB * HH)
                                           : P.pipe16 + (size_t)((d & 1) * LL + l) * (BB * HH);
                            op = P.H1st + (size_t)l * HH; os = LL * HH;
                            d32 = P.h1m32 + (size_t)l * (BB * HH); ds = HH;
                            d16 = P.h1m16 + (size_t)l * (BB * HH);
                        } else {
                            alo = P.h0m16 + (size_t)l * (BB * HH);
                            op = P.h1m32 + (size_t)l * (BB * HH); os = HH;
                            d32 = P.H1st + (size_t)l * HH; ds = LL * HH;
                            d16 = P.h1f16 + (size_t)l * (BB * HH);
                        }
                        ahi = P.a0hi + (size_t)l * (BB * HH);
                        wTp = P.g0T + (size_t)w * (512 * 1024);
                        bp  = P.g0_b + (size_t)w * 512;
                        zp  = P.z1 + (size_t)l * (BB * HH);
                    } else {
                        // g1: A=[h1 | h0*q] -> h1_cap; new h0 = z0*hc + (1-z0)*h0
                        if (j == 0) {
                            alo = P.h1f16 + (size_t)l * (BB * HH);
                            op = (l == 0) ? P.H0in + (size_t)t * HH
                                          : P.pipe32 + (size_t)((d & 1) * LL + l) * (BB * HH);
                            os = (l == 0) ? (TT * HH) : HH;
                            d32 = P.h0m32 + (size_t)l * (BB * HH); ds = HH;
                            d16 = P.h0m16 + (size_t)l * (BB * HH);
                        } else {
                            alo = P.h1m16 + (size_t)l * (BB * HH);
                            op = P.h0m32 + (size_t)l * (BB * HH); os = HH;
                            if (l == LL - 1) {
                                d32 = P.H0out + (size_t)t * HH; ds = TT * HH; d16 = nullptr;
                            } else {
                                d32 = P.pipe32 + (size_t)(((d + 1) & 1) * LL + (l + 1)) * (BB * HH); ds = HH;
                                d16 = P.pipe16 + (size_t)(((d + 1) & 1) * LL + (l + 1)) * (BB * HH);
                            }
                        }
                        ahi = P.a1hi + (size_t)l * (BB * HH);
                        wTp = P.g1T + (size_t)w * (512 * 1024);
                        bp  = P.g1_b + (size_t)w * 512;
                        zp  = P.z0 + (size_t)l * (BB * HH);
                    }
                    s2_tile(alo, ahi, wTp, bp, zp, op, os, d32, ds, d16,
                            n0, tid, lane, wid, Al, Bl);
                } else {
                    // convert H0in[:, d+1, :] -> h0c[(d+1)&1] for next diagonal
                    int ct = tile - nt2;            // 0..15
                    int tn = d + 1;
                    int m = ct * 8 + (tid >> 5);
                    int k = (tid & 31) * 16;
                    const float* s = P.H0in + (size_t)m * (TT * HH) + (size_t)tn * HH + k;
                    f16* dd = P.h0c + (size_t)(tn & 1) * (BB * HH) + (size_t)m * HH + k;
                    float4 a  = *(const float4*)(s);
                    float4 b  = *(const float4*)(s + 4);
                    float4 c2 = *(const float4*)(s + 8);
                    float4 e  = *(const float4*)(s + 12);
                    f16x8 r0, r1;
                    r0[0]=(f16)a.x;  r0[1]=(f16)a.y;  r0[2]=(f16)a.z;  r0[3]=(f16)a.w;
                    r0[4]=(f16)b.x;  r0[5]=(f16)b.y;  r0[6]=(f16)b.z;  r0[7]=(f16)b.w;
                    r1[0]=(f16)c2.x; r1[1]=(f16)c2.y; r1[2]=(f16)c2.z; r1[3]=(f16)c2.w;
                    r1[4]=(f16)e.x;  r1[5]=(f16)e.y;  r1[6]=(f16)e.z;  r1[7]=(f16)e.w;
                    ast16(dd, r0);
                    ast16(dd + 8, r1);
                }
            }
            gsync(P.bar, bid, ph++);
        }
    }
}

// ---------------------------------------------------------------------------
// Host side
// ---------------------------------------------------------------------------
extern "C" void kernel_launch(void* const* d_in, const int* in_sizes, int n_in,
                              void* d_out, int out_size, void* d_ws, size_t ws_size,
                              hipStream_t stream)
{
    (void)in_sizes; (void)n_in; (void)out_size; (void)ws_size;

    const float* H0in  = (const float*)d_in[0];
    const float* lin_w = (const float*)d_in[1];
    const float* lin_b = (const float*)d_in[2];
    const float* g0_w  = (const float*)d_in[3];
    const float* g0_b  = (const float*)d_in[4];
    const float* g1_w  = (const float*)d_in[5];
    const float* g1_b  = (const float*)d_in[6];

    float* H0out = (float*)d_out;                       // (B,T,H)
    float* H1st  = H0out + (size_t)BB * TT * HH;        // (B,L,H)

    // Workspace layout (~58 MB)
    char* p = (char*)d_ws;
    f16* linT = (f16*)p;  p += (size_t)LL * JJ * 2048 * 1024 * sizeof(f16); // 32 MB
    f16* g0T  = (f16*)p;  p += (size_t)LL * JJ * 512 * 1024 * sizeof(f16);  //  8 MB
    f16* g1T  = (f16*)p;  p += (size_t)LL * JJ * 512 * 1024 * sizeof(f16);  //  8 MB
    f16* h1f16 = (f16*)p; p += (size_t)LL * BB * HH * sizeof(f16);
    float* pipe32 = (float*)p; p += (size_t)2 * LL * BB * HH * sizeof(float);
    f16* pipe16 = (f16*)p;     p += (size_t)2 * LL * BB * HH * sizeof(f16);
    float* h0m32 = (float*)p;  p += (size_t)LL * BB * HH * sizeof(float);
    f16* h0m16 = (f16*)p;      p += (size_t)LL * BB * HH * sizeof(f16);
    float* h1m32 = (float*)p;  p += (size_t)LL * BB * HH * sizeof(float);
    f16* h1m16 = (f16*)p;      p += (size_t)LL * BB * HH * sizeof(f16);
    f16* a0hi = (f16*)p;       p += (size_t)LL * BB * HH * sizeof(f16);
    f16* a1hi = (f16*)p;       p += (size_t)LL * BB * HH * sizeof(f16);
    float* z0b = (float*)p;    p += (size_t)LL * BB * HH * sizeof(float);
    float* z1b = (float*)p;    p += (size_t)LL * BB * HH * sizeof(float);
    f16* h0c = (f16*)p;        p += (size_t)2 * BB * HH * sizeof(f16);
    unsigned* bar = (unsigned*)p; p += 4096;

    // One-time (per call) weight fp16 transposes
    wt_transpose_cvt<<<dim3(32, 64, 8), 256, 0, stream>>>(lin_w, linT, 1024, 2048);
    wt_transpose_cvt<<<dim3(32, 16, 8), 256, 0, stream>>>(g0_w,  g0T,  1024, 512);
    wt_transpose_cvt<<<dim3(32, 16, 8), 256, 0, stream>>>(g1_w,  g1T,  1024, 512);
    hipMemsetAsync(H1st, 0, (size_t)BB * LL * HH * sizeof(float), stream);
    hipMemsetAsync(bar, 0, 4096, stream);

    PK P;
    P.H0in = H0in; P.lin_b = lin_b; P.g0_b = g0_b; P.g1_b = g1_b;
    P.linT = linT; P.g0T = g0T; P.g1T = g1T;
    P.H0out = H0out; P.H1st = H1st;
    P.h1f16 = h1f16; P.pipe32 = pipe32; P.pipe16 = pipe16;
    P.h0m32 = h0m32; P.h0m16 = h0m16; P.h1m32 = h1m32; P.h1m16 = h1m16;
    P.a0hi = a0hi; P.a1hi = a1hi; P.z0 = z0b; P.z1 = z1b;
    P.h0c = h0c; P.bar = bar;

    // Cooperative launch: runtime guarantees all NBLK blocks are co-resident
    // (or fails cleanly). Fallback to plain launch if coop is unavailable.
    void* args[] = { (void*)&P };
    hipError_t e = hipLaunchCooperativeKernel((const void*)lattice_persistent,
                                              dim3(NBLK), dim3(256), args, 0, stream);
    if (e != hipSuccess) {
        lattice_persistent<<<dim3(NBLK), 256, 0, stream>>>(P);
    }
}

// Round 5
// 29733.734 us; speedup vs baseline: 1.9259x; 1.2405x over previous
//
#include <hip/hip_runtime.h>

// Problem constants
#define HH 512
#define BB 128
#define TT 512
#define LL 4
#define JJ 2
#define NBLK 256   // persistent grid size (cooperative launch => co-resident)
#define SPIN_LIMIT 50000
#define PFD 4      // prefetch FIFO depth (K-iters ahead); covers ~HBM latency

typedef _Float16 f16;
typedef __attribute__((ext_vector_type(4))) _Float16 f16x4;
typedef __attribute__((ext_vector_type(8))) _Float16 f16x8;
typedef __attribute__((ext_vector_type(4))) float f32x4;

#define AR __ATOMIC_RELAXED
#define AS __HIP_MEMORY_SCOPE_AGENT

// ---------------------------------------------------------------------------
// Agent-scope (sc0 sc1: L1+L2 bypass, coherent at L3) access helpers.
// Used for ALL mutable cross-block data. Weights/bias/H0in use normal cached
// loads and stay L2-resident.
// ---------------------------------------------------------------------------
__device__ __forceinline__ f16x8 ald16(const f16* p) {
    union { unsigned long long u[2]; f16x8 v; } r;
    const unsigned long long* q = (const unsigned long long*)p;
    r.u[0] = __hip_atomic_load(q, AR, AS);
    r.u[1] = __hip_atomic_load(q + 1, AR, AS);
    return r.v;
}
__device__ __forceinline__ void ast16(f16* p, f16x8 v) {
    union { f16x8 v; unsigned long long u[2]; } r; r.v = v;
    unsigned long long* q = (unsigned long long*)p;
    __hip_atomic_store(q, r.u[0], AR, AS);
    __hip_atomic_store(q + 1, r.u[1], AR, AS);
}
__device__ __forceinline__ float aldf(const float* p) { return __hip_atomic_load(p, AR, AS); }
__device__ __forceinline__ void astf(float* p, float v) { __hip_atomic_store(p, v, AR, AS); }
__device__ __forceinline__ f16 aldh(const f16* p) {
    unsigned short u = __hip_atomic_load((const unsigned short*)p, AR, AS);
    union { unsigned short s; f16 h; } c; c.s = u; return c.h;
}
__device__ __forceinline__ void asth(f16* p, f16 v) {
    union { f16 h; unsigned short s; } c; c.h = v;
    __hip_atomic_store((unsigned short*)p, c.s, AR, AS);
}

// ---------------------------------------------------------------------------
// Weight convert + transpose: src fp32 [mat][K][N] -> dst fp16 [mat][N][K]
// ---------------------------------------------------------------------------
__global__ __launch_bounds__(256) void wt_transpose_cvt(
    const float* __restrict__ src, f16* __restrict__ dst, int K, int N)
{
    __shared__ f16 tile[32][33];
    const size_t mat = blockIdx.z;
    const float* s = src + mat * (size_t)K * N;
    f16* d = dst + mat * (size_t)K * N;
    const int k0 = blockIdx.x * 32, n0 = blockIdx.y * 32;
    const int tx = threadIdx.x & 31, ty = threadIdx.x >> 5; // 32 x 8
#pragma unroll
    for (int i = 0; i < 4; i++) {
        int k = k0 + ty + 8 * i;
        tile[ty + 8 * i][tx] = (f16)s[(size_t)k * N + n0 + tx];
    }
    __syncthreads();
#pragma unroll
    for (int i = 0; i < 4; i++) {
        int n = n0 + ty + 8 * i;
        d[(size_t)n * K + k0 + tx] = tile[tx][ty + 8 * i];
    }
}

// ---------------------------------------------------------------------------
// Persistent-kernel parameter block
// ---------------------------------------------------------------------------
struct PK {
    const float* H0in;
    const float* lin_b;
    const float* g0_b;
    const float* g1_b;
    const f16* linT;   // [L][J][2048][1024]
    const f16* g0T;    // [L][J][512][1024]
    const f16* g1T;
    float* H0out;      // (B,T,H)
    float* H1st;       // (B,L,H) f32 state, lives in d_out
    f16*   h1f16;      // [L][B][H] fp16 mirror of H1st
    float* pipe32;     // [2][L][B][H] h0 between layers (parity d&1)
    f16*   pipe16;
    float* h0m32; f16* h0m16;   // [L][B][H] j-intermediate h0
    float* h1m32; f16* h1m16;   // [L][B][H] j-intermediate h1
    f16* a0hi; f16* a1hi;       // [L][B][H] gated halves h1*r, h0*q
    float* z0; float* z1;       // [L][B][H] gates
    f16* h0c;                   // [2][B][H] fp16 of H0in[:,t,:] (parity t&1)
    unsigned* bar;              // barrier block
};

// Versioned two-level grid barrier, NO cache-maintenance fences.
//   bar[0]            = generation (monotonic)
//   bar[32]           = root counter (monotonic)
//   bar[64 + g*32]    = group-g counter (g = bid & 15), monotonic
//   bar[576]          = sticky broken flag
// Release: s_waitcnt vmcnt(0) before arrival => all this block's agent-scope
// stores have reached L3 (the coherence point). Acquire: consumer loads are
// agent-scope (L1/L2 bypass) and control-depend on the gen flip.
__device__ inline void gsync(unsigned* bar, int bid, unsigned ph)
{
    __syncthreads();
    if (threadIdx.x == 0) {
        unsigned* gen  = bar;
        unsigned* root = bar + 32;
        unsigned* gcnt = bar + 64 + (bid & 15) * 32;
        unsigned* brk  = bar + 576;
        if (__hip_atomic_load(brk, AR, AS) == 0u) {
            asm volatile("s_waitcnt vmcnt(0)" ::: "memory"); // release
            unsigned prev = __hip_atomic_fetch_add(gcnt, 1u, AR, AS);
            if (prev == ph * 16u + 15u) {                    // group leader
                unsigned r = __hip_atomic_fetch_add(root, 1u, AR, AS);
                if (r == ph * 16u + 15u) {                   // last group
                    __hip_atomic_store(gen, ph + 1u, AR, AS);
                }
            }
            unsigned spins = 0;
            while ((int)(__hip_atomic_load(gen, AR, AS) - (ph + 1u)) < 0) {
                __builtin_amdgcn_s_sleep(1);
                if (++spins > SPIN_LIMIT) {
                    __hip_atomic_store(brk, 1u, AR, AS);
                    break;
                }
                if (__hip_atomic_load(brk, AR, AS) != 0u) break;
            }
        }
        asm volatile("" ::: "memory");
    }
    __syncthreads();
}

// ---------------------------------------------------------------------------
// Stage 1 tile: g = sigmoid([h0|h1] @ lin_w + b). M=128, N=32 (BN=32), K=1024.
// Depth-PFD register-FIFO prefetch (T3/T4 via compiler-counted vmcnt):
// at iter it, issue loads for it+PFD; ds_write it+1's regs (landed ~3 iters
// ago). LDS double-buffered, one __syncthreads per K-step.
// Epilogue by column class: 0 -> z0, 1 -> z1, 2 -> a0hi = h1*r, 3 -> a1hi = h0*q
// ---------------------------------------------------------------------------
__device__ __forceinline__ void s1_tile(
    const f16* __restrict__ alo, const f16* __restrict__ ahi,
    const f16* __restrict__ wT, const float* __restrict__ bias,
    float* __restrict__ z0, float* __restrict__ z1,
    f16* __restrict__ a0hi, f16* __restrict__ a1hi,
    int n0, int tid, int lane, int wid,
    f16 (*Al)[72], f16 (*Bl)[72])
{
    const int wm = wid & 1;
    const int wn = wid >> 1;
    const int kc = tid & 7;   // 8 k-groups of 8 halves = 64 k
    const int rb = tid >> 3;  // 32-row base
    f32x4 acc[4] = {};
    f16x8 fa[PFD][4];         // A FIFO (static-indexed under full unroll)
    f16x8 fb[PFD];            // B FIFO

    auto LOAD = [&](int p, int K0) {
        const f16* ab = (K0 < 512 ? alo : ahi) + (K0 & 511) + kc * 8;
        fa[p][0] = ald16(ab + (size_t)(rb)      * 512);
        fa[p][1] = ald16(ab + (size_t)(rb + 32) * 512);
        fa[p][2] = ald16(ab + (size_t)(rb + 64) * 512);
        fa[p][3] = ald16(ab + (size_t)(rb + 96) * 512);
        fb[p] = *(const f16x8*)(wT + (size_t)(n0 + rb) * 1024 + K0 + kc * 8);
    };
    auto WRITE = [&](int buf, int p) {
        *(f16x8*)(&Al[buf * 128 + rb     ][kc * 8]) = fa[p][0];
        *(f16x8*)(&Al[buf * 128 + rb + 32][kc * 8]) = fa[p][1];
        *(f16x8*)(&Al[buf * 128 + rb + 64][kc * 8]) = fa[p][2];
        *(f16x8*)(&Al[buf * 128 + rb + 96][kc * 8]) = fa[p][3];
        *(f16x8*)(&Bl[buf * 32 + rb][kc * 8]) = fb[p];
    };

#pragma unroll
    for (int p = 0; p < PFD; ++p) LOAD(p, p * 64);
    WRITE(0, 0);
    __syncthreads();
#pragma unroll
    for (int it = 0; it < 16; ++it) {
        const int cur = it & 1;
        if (it + PFD < 16) LOAD((it + PFD) % PFD, (it + PFD) * 64);
#pragma unroll
        for (int ks = 0; ks < 2; ++ks) {
            const int kl = ks * 32 + (lane >> 4) * 8;
            f16x8 bf = *(const f16x8*)(&Bl[cur * 32 + wn * 16 + (lane & 15)][kl]);
#pragma unroll
            for (int fm = 0; fm < 4; fm++) {
                f16x8 af = *(const f16x8*)(&Al[cur * 128 + wm * 64 + fm * 16 + (lane & 15)][kl]);
                acc[fm] = __builtin_amdgcn_mfma_f32_16x16x32_f16(af, bf, acc[fm], 0, 0, 0);
            }
        }
        if (it < 15) { WRITE(cur ^ 1, (it + 1) % PFD); __syncthreads(); }
    }

    const int cls = n0 >> 9;
#pragma unroll
    for (int fm = 0; fm < 4; fm++) {
#pragma unroll
        for (int r = 0; r < 4; r++) {
            int m = wm * 64 + fm * 16 + (lane >> 4) * 4 + r;
            int n = n0 + wn * 16 + (lane & 15);
            float x = acc[fm][r] + bias[n];
            float s = 1.0f / (1.0f + __expf(-x));
            int nn = n & 511;
            if (cls == 0)      astf(z0 + m * 512 + nn, s);
            else if (cls == 1) astf(z1 + m * 512 + nn, s);
            else if (cls == 2) asth(a0hi + m * 512 + nn, (f16)((float)aldh(ahi + m * 512 + nn) * s));
            else               asth(a1hi + m * 512 + nn, (f16)((float)aldh(alo + m * 512 + nn) * s));
        }
    }
}

// ---------------------------------------------------------------------------
// Stage 2 tile: hc = tanh(A @ gw + gb); dst = z*hc + (1-z)*old.
// M=128, N=16 (BN=16), K=1024, depth-PFD pipelined like s1.
// 4 waves split M 4-way (32 rows each), acc[2] frags, all waves share B frag.
// ---------------------------------------------------------------------------
__device__ __forceinline__ void s2_tile(
    const f16* __restrict__ alo, const f16* __restrict__ ahi,
    const f16* __restrict__ wT, const float* __restrict__ bias,
    const float* __restrict__ zg, const float* __restrict__ oldp, int olds,
    float* __restrict__ dst32, int dsts, f16* __restrict__ dst16,
    int n0, int tid, int lane, int wid,
    f16 (*Al)[72], f16 (*Bl)[72])
{
    const int kc  = tid & 7;
    const int rb  = tid >> 3;
    const int kc2 = tid & 15;  // 16 k-groups of 4 halves = 64 k
    const int rb2 = tid >> 4;  // 16 rows
    f32x4 acc[2] = {};
    f16x8 fa[PFD][4];
    f16x4 fb[PFD];

    auto LOAD = [&](int p, int K0) {
        const f16* ab = (K0 < 512 ? alo : ahi) + (K0 & 511) + kc * 8;
        fa[p][0] = ald16(ab + (size_t)(rb)      * 512);
        fa[p][1] = ald16(ab + (size_t)(rb + 32) * 512);
        fa[p][2] = ald16(ab + (size_t)(rb + 64) * 512);
        fa[p][3] = ald16(ab + (size_t)(rb + 96) * 512);
        fb[p] = *(const f16x4*)(wT + (size_t)(n0 + rb2) * 1024 + K0 + kc2 * 4);
    };
    auto WRITE = [&](int buf, int p) {
        *(f16x8*)(&Al[buf * 128 + rb     ][kc * 8]) = fa[p][0];
        *(f16x8*)(&Al[buf * 128 + rb + 32][kc * 8]) = fa[p][1];
        *(f16x8*)(&Al[buf * 128 + rb + 64][kc * 8]) = fa[p][2];
        *(f16x8*)(&Al[buf * 128 + rb + 96][kc * 8]) = fa[p][3];
        *(f16x4*)(&Bl[buf * 16 + rb2][kc2 * 4]) = fb[p];
    };

#pragma unroll
    for (int p = 0; p < PFD; ++p) LOAD(p, p * 64);
    WRITE(0, 0);
    __syncthreads();
#pragma unroll
    for (int it = 0; it < 16; ++it) {
        const int cur = it & 1;
        if (it + PFD < 16) LOAD((it + PFD) % PFD, (it + PFD) * 64);
#pragma unroll
        for (int ks = 0; ks < 2; ++ks) {
            const int kl = ks * 32 + (lane >> 4) * 8;
            f16x8 bf = *(const f16x8*)(&Bl[cur * 16 + (lane & 15)][kl]);
#pragma unroll
            for (int fm = 0; fm < 2; fm++) {
                f16x8 af = *(const f16x8*)(&Al[cur * 128 + wid * 32 + fm * 16 + (lane & 15)][kl]);
                acc[fm] = __builtin_amdgcn_mfma_f32_16x16x32_f16(af, bf, acc[fm], 0, 0, 0);
            }
        }
        if (it < 15) { WRITE(cur ^ 1, (it + 1) % PFD); __syncthreads(); }
    }

#pragma unroll
    for (int fm = 0; fm < 2; fm++) {
#pragma unroll
        for (int r = 0; r < 4; r++) {
            int m = wid * 32 + fm * 16 + (lane >> 4) * 4 + r;
            int n = n0 + (lane & 15);
            float hc  = tanhf(acc[fm][r] + bias[n]);
            float zv  = aldf(zg + m * 512 + n);
            float old = aldf(oldp + (size_t)m * olds + n);
            float v = zv * hc + (1.0f - zv) * old;
            astf(dst32 + (size_t)m * dsts + n, v);
            if (dst16) asth(dst16 + m * 512 + n, (f16)v);
        }
    }
}

// ---------------------------------------------------------------------------
// Persistent kernel: whole wavefront in one launch, phases split across all
// 256 CUs (s1: nc*64 tiles BN=32; s2: nc*64 tiles BN=16), versioned barrier.
// ---------------------------------------------------------------------------
__global__ __launch_bounds__(256, 1) void lattice_persistent(PK P)
{
    __shared__ __attribute__((aligned(16))) f16 Al[2 * 128][72];
    __shared__ __attribute__((aligned(16))) f16 Bl[2 * 32][72];

    const int tid  = threadIdx.x;
    const int lane = tid & 63;
    const int wid  = tid >> 6;
    const int bid  = blockIdx.x;
    unsigned ph = 0;

    // ---- prologue: zero h1 fp16 mirror; convert H0in[:,0,:] -> h0c[0]
    {
        int g = bid * 256 + tid;                 // 0..65535
        if (g < 32768) {
            f16x8 zz = {};
            ast16(P.h1f16 + (size_t)g * 8, zz);  // 32768 vectors exactly
        }
        int m = g >> 9;
        int k = g & 511;
        asth(P.h0c + (size_t)m * HH + k, (f16)P.H0in[(size_t)m * (TT * HH) + k]);
    }
    gsync(P.bar, bid, ph++);

    for (int d = 0; d < TT + LL - 1; ++d) {
        int lmin = d - (TT - 1); if (lmin < 0) lmin = 0;
        int lmax = d < LL - 1 ? d : LL - 1;
        int nc = lmax - lmin + 1;
        for (int j = 0; j < JJ; ++j) {
            // ================= stage 1 phase: nc*64 tiles (BN=32) ==========
            int nt1 = nc * 64;
            for (int tile = bid; tile < nt1; tile += NBLK) {
                int l = lmin + (tile >> 6);
                int n0 = (tile & 63) * 32;
                int w = l * JJ + j;
                const f16 *alo, *ahi;
                if (j == 0) {
                    alo = (l == 0) ? P.h0c + (size_t)(d & 1) * (BB * HH)
                                   : P.pipe16 + (size_t)((d & 1) * LL + l) * (BB * HH);
                    ahi = P.h1f16 + (size_t)l * (BB * HH);
                } else {
                    alo = P.h0m16 + (size_t)l * (BB * HH);
                    ahi = P.h1m16 + (size_t)l * (BB * HH);
                }
                s1_tile(alo, ahi,
                        P.linT + (size_t)w * (2048 * 1024),
                        P.lin_b + (size_t)w * 2048,
                        P.z0 + (size_t)l * (BB * HH), P.z1 + (size_t)l * (BB * HH),
                        P.a0hi + (size_t)l * (BB * HH), P.a1hi + (size_t)l * (BB * HH),
                        n0, tid, lane, wid, Al, Bl);
            }
            gsync(P.bar, bid, ph++);

            // ========== stage 2 phase: nc*64 tiles BN=16 (+16 conv) ========
            int nt2 = nc * 64;
            bool cv = (j == 1) && (d + 1 < TT);
            int ntt = nt2 + (cv ? 16 : 0);
            for (int tile = bid; tile < ntt; tile += NBLK) {
                if (tile < nt2) {
                    int ci = tile >> 6;
                    int rem = tile & 63;
                    int gi = rem >> 5;          // 0: g0 (-> new h1), 1: g1 (-> new h0)
                    int n0 = (rem & 31) * 16;
                    int l = lmin + ci, t = d - l;
                    int w = l * JJ + j;
                    const f16 *alo, *ahi, *wTp;
                    const float *bp, *zp, *op;
                    int os, ds;
                    float* d32; f16* d16;
                    if (gi == 0) {
                        // g0: A=[h0 | h1*r] -> h0_cap; new h1 = z1*hc + (1-z1)*h1
                        if (j == 0) {
                            alo = (l == 0) ? P.h0c + (size_t)(d & 1) * (BB * HH)
                                           : P.pipe16 + (size_t)((d & 1) * LL + l) * (BB * HH);
                            op = P.H1st + (size_t)l * HH; os = LL * HH;
                            d32 = P.h1m32 + (size_t)l * (BB * HH); ds = HH;
                            d16 = P.h1m16 + (size_t)l * (BB * HH);
                        } else {
                            alo = P.h0m16 + (size_t)l * (BB * HH);
                            op = P.h1m32 + (size_t)l * (BB * HH); os = HH;
                            d32 = P.H1st + (size_t)l * HH; ds = LL * HH;
                            d16 = P.h1f16 + (size_t)l * (BB * HH);
                        }
                        ahi = P.a0hi + (size_t)l * (BB * HH);
                        wTp = P.g0T + (size_t)w * (512 * 1024);
                        bp  = P.g0_b + (size_t)w * 512;
                        zp  = P.z1 + (size_t)l * (BB * HH);
                    } else {
                        // g1: A=[h1 | h0*q] -> h1_cap; new h0 = z0*hc + (1-z0)*h0
                        if (j == 0) {
                            alo = P.h1f16 + (size_t)l * (BB * HH);
                            op = (l == 0) ? P.H0in + (size_t)t * HH
                                          : P.pipe32 + (size_t)((d & 1) * LL + l) * (BB * HH);
                            os = (l == 0) ? (TT * HH) : HH;
                            d32 = P.h0m32 + (size_t)l * (BB * HH); ds = HH;
                            d16 = P.h0m16 + (size_t)l * (BB * HH);
                        } else {
                            alo = P.h1m16 + (size_t)l * (BB * HH);
                            op = P.h0m32 + (size_t)l * (BB * HH); os = HH;
                            if (l == LL - 1) {
                                d32 = P.H0out + (size_t)t * HH; ds = TT * HH; d16 = nullptr;
                            } else {
                                d32 = P.pipe32 + (size_t)(((d + 1) & 1) * LL + (l + 1)) * (BB * HH); ds = HH;
                                d16 = P.pipe16 + (size_t)(((d + 1) & 1) * LL + (l + 1)) * (BB * HH);
                            }
                        }
                        ahi = P.a1hi + (size_t)l * (BB * HH);
                        wTp = P.g1T + (size_t)w * (512 * 1024);
                        bp  = P.g1_b + (size_t)w * 512;
                        zp  = P.z0 + (size_t)l * (BB * HH);
                    }
                    s2_tile(alo, ahi, wTp, bp, zp, op, os, d32, ds, d16,
                            n0, tid, lane, wid, Al, Bl);
                } else {
                    // convert H0in[:, d+1, :] -> h0c[(d+1)&1] for next diagonal
                    int ct = tile - nt2;            // 0..15
                    int tn = d + 1;
                    int m = ct * 8 + (tid >> 5);
                    int k = (tid & 31) * 16;
                    const float* s = P.H0in + (size_t)m * (TT * HH) + (size_t)tn * HH + k;
                    f16* dd = P.h0c + (size_t)(tn & 1) * (BB * HH) + (size_t)m * HH + k;
                    float4 a  = *(const float4*)(s);
                    float4 b  = *(const float4*)(s + 4);
                    float4 c2 = *(const float4*)(s + 8);
                    float4 e  = *(const float4*)(s + 12);
                    f16x8 r0, r1;
                    r0[0]=(f16)a.x;  r0[1]=(f16)a.y;  r0[2]=(f16)a.z;  r0[3]=(f16)a.w;
                    r0[4]=(f16)b.x;  r0[5]=(f16)b.y;  r0[6]=(f16)b.z;  r0[7]=(f16)b.w;
                    r1[0]=(f16)c2.x; r1[1]=(f16)c2.y; r1[2]=(f16)c2.z; r1[3]=(f16)c2.w;
                    r1[4]=(f16)e.x;  r1[5]=(f16)e.y;  r1[6]=(f16)e.z;  r1[7]=(f16)e.w;
                    ast16(dd, r0);
                    ast16(dd + 8, r1);
                }
            }
            gsync(P.bar, bid, ph++);
        }
    }
}

// ---------------------------------------------------------------------------
// Host side
// ---------------------------------------------------------------------------
extern "C" void kernel_launch(void* const* d_in, const int* in_sizes, int n_in,
                              void* d_out, int out_size, void* d_ws, size_t ws_size,
                              hipStream_t stream)
{
    (void)in_sizes; (void)n_in; (void)out_size; (void)ws_size;

    const float* H0in  = (const float*)d_in[0];
    const float* lin_w = (const float*)d_in[1];
    const float* lin_b = (const float*)d_in[2];
    const float* g0_w  = (const float*)d_in[3];
    const float* g0_b  = (const float*)d_in[4];
    const float* g1_w  = (const float*)d_in[5];
    const float* g1_b  = (const float*)d_in[6];

    float* H0out = (float*)d_out;                       // (B,T,H)
    float* H1st  = H0out + (size_t)BB * TT * HH;        // (B,L,H)

    // Workspace layout (~58 MB)
    char* p = (char*)d_ws;
    f16* linT = (f16*)p;  p += (size_t)LL * JJ * 2048 * 1024 * sizeof(f16); // 32 MB
    f16* g0T  = (f16*)p;  p += (size_t)LL * JJ * 512 * 1024 * sizeof(f16);  //  8 MB
    f16* g1T  = (f16*)p;  p += (size_t)LL * JJ * 512 * 1024 * sizeof(f16);  //  8 MB
    f16* h1f16 = (f16*)p; p += (size_t)LL * BB * HH * sizeof(f16);
    float* pipe32 = (float*)p; p += (size_t)2 * LL * BB * HH * sizeof(float);
    f16* pipe16 = (f16*)p;     p += (size_t)2 * LL * BB * HH * sizeof(f16);
    float* h0m32 = (float*)p;  p += (size_t)LL * BB * HH * sizeof(float);
    f16* h0m16 = (f16*)p;      p += (size_t)LL * BB * HH * sizeof(f16);
    float* h1m32 = (float*)p;  p += (size_t)LL * BB * HH * sizeof(float);
    f16* h1m16 = (f16*)p;      p += (size_t)LL * BB * HH * sizeof(f16);
    f16* a0hi = (f16*)p;       p += (size_t)LL * BB * HH * sizeof(f16);
    f16* a1hi = (f16*)p;       p += (size_t)LL * BB * HH * sizeof(f16);
    float* z0b = (float*)p;    p += (size_t)LL * BB * HH * sizeof(float);
    float* z1b = (float*)p;    p += (size_t)LL * BB * HH * sizeof(float);
    f16* h0c = (f16*)p;        p += (size_t)2 * BB * HH * sizeof(f16);
    unsigned* bar = (unsigned*)p; p += 4096;

    // One-time (per call) weight fp16 transposes
    wt_transpose_cvt<<<dim3(32, 64, 8), 256, 0, stream>>>(lin_w, linT, 1024, 2048);
    wt_transpose_cvt<<<dim3(32, 16, 8), 256, 0, stream>>>(g0_w,  g0T,  1024, 512);
    wt_transpose_cvt<<<dim3(32, 16, 8), 256, 0, stream>>>(g1_w,  g1T,  1024, 512);
    hipMemsetAsync(H1st, 0, (size_t)BB * LL * HH * sizeof(float), stream);
    hipMemsetAsync(bar, 0, 4096, stream);

    PK P;
    P.H0in = H0in; P.lin_b = lin_b; P.g0_b = g0_b; P.g1_b = g1_b;
    P.linT = linT; P.g0T = g0T; P.g1T = g1T;
    P.H0out = H0out; P.H1st = H1st;
    P.h1f16 = h1f16; P.pipe32 = pipe32; P.pipe16 = pipe16;
    P.h0m32 = h0m32; P.h0m16 = h0m16; P.h1m32 = h1m32; P.h1m16 = h1m16;
    P.a0hi = a0hi; P.a1hi = a1hi; P.z0 = z0b; P.z1 = z1b;
    P.h0c = h0c; P.bar = bar;

    // Cooperative launch: runtime guarantees all NBLK blocks are co-resident
    // (or fails cleanly). Fallback to plain launch if coop is unavailable.
    void* args[] = { (void*)&P };
    hipError_t e = hipLaunchCooperativeKernel((const void*)lattice_persistent,
                                              dim3(NBLK), dim3(256), args, 0, stream);
    if (e != hipSuccess) {
        lattice_persistent<<<dim3(NBLK), 256, 0, stream>>>(P);
    }
}